// Round 3
// baseline (7515.591 us; speedup 1.0000x reference)
//
#include <hip/hip_runtime.h>
#include <hip/hip_bf16.h>

using bf16 = __hip_bfloat16;
#define DEVI __device__ __forceinline__

constexpr int B = 64, T = 24, N = 256, F1 = 64, F2 = 128;

DEVI float b2f(bf16 v) { return __bfloat162float(v); }
DEVI float hsig(float x) { x = x * 0.2f + 0.5f; return fminf(fmaxf(x, 0.f), 1.f); }

// ---------- dtype detection: count bf16 NaN/Inf patterns in first 65536 u16 of x ----------
// flag = 1 -> inputs are bf16 ; flag = 0 -> inputs are fp32
__global__ void detect_kernel(const unsigned short* __restrict__ xu, int* __restrict__ flag) {
    __shared__ int red[256];
    int tid = threadIdx.x;
    int cnt = 0;
    for (int i = tid; i < 65536; i += 256) {
        unsigned short u = xu[i];
        if (((u >> 7) & 0xFF) == 0xFF) cnt++;   // bf16 exp all-ones => NaN/Inf
    }
    red[tid] = cnt; __syncthreads();
    for (int k = 128; k > 0; k >>= 1) {
        if (tid < k) red[tid] += red[tid + k];
        __syncthreads();
    }
    if (tid == 0) *flag = (red[0] == 0) ? 1 : 0;
}

// ---------- universal input -> f32 conversion ----------
__global__ void cvt_any(const void* __restrict__ s, float* __restrict__ d, int n,
                        const int* __restrict__ flag) {
    int i = blockIdx.x * 256 + threadIdx.x;
    if (i >= n) return;
    if (*flag) d[i] = b2f(((const bf16*)s)[i]);
    else       d[i] = ((const float*)s)[i];
}

// ---------- per-t slice: conv1(3x3,1->64) fused into conv2(3x3,64->64) ----------
// grid (8, B): 32 n-positions per block, all 64 f. Output xs[b][n][f] for time t.
__global__ __launch_bounds__(256)
void conv_slice_kernel(const float* __restrict__ x, const float* __restrict__ w1c,
                       const float* __restrict__ b1v, const float* __restrict__ w2c,
                       const float* __restrict__ b2v, float* __restrict__ xs, int t) {
    __shared__ float s1[3 * 34 * 64];   // conv1 values: tt=t-1..t+1, nn=n0-1..n0+32, c
    __shared__ float sxw[5 * 36];       // x window: rows t-2..t+2, cols n0-2..n0+33
    int b = blockIdx.y, n0 = blockIdx.x * 32, tid = threadIdx.x;
    for (int i = tid; i < 180; i += 256) {
        int r = i / 36, cc = i - r * 36;
        int tt = t - 2 + r, nn = n0 - 2 + cc;
        float v = 0.f;
        if (tt >= 0 && tt < T && nn >= 0 && nn < N) v = x[(b * T + tt) * N + nn];
        sxw[i] = v;
    }
    __syncthreads();
    // conv1 on the fly; zero outside valid (tt,nn) to replicate conv2's SAME padding
    for (int i = tid; i < 3 * 34 * 64; i += 256) {
        int c = i & 63, q = i >> 6;
        int tti = q / 34, p = q - tti * 34;
        int tt = t - 1 + tti, nn = n0 + p - 1;
        float v = 0.f;
        if (tt >= 0 && tt < T && nn >= 0 && nn < N) {
            v = b1v[c];
            for (int dt = 0; dt < 3; dt++)
#pragma unroll
                for (int dn = 0; dn < 3; dn++)
                    v += sxw[(tti + dt) * 36 + (p + dn)] * w1c[(dt * 3 + dn) * 64 + c];
        }
        s1[i] = v;
    }
    __syncthreads();
    int f = tid & 63, ng = tid >> 6;
    int nb = ng * 8;
    float bv = b2v[f];
    float acc[8];
#pragma unroll
    for (int j = 0; j < 8; j++) acc[j] = bv;
    for (int kt = 0; kt < 3; kt++)
        for (int kn = 0; kn < 3; kn++)
            for (int c = 0; c < 64; c++) {
                float w = w2c[((kt * 3 + kn) * 64 + c) * 64 + f];
                int base = (kt * 34 + nb + kn) * 64 + c;
#pragma unroll
                for (int j = 0; j < 8; j++) acc[j] += w * s1[base + j * 64];
            }
#pragma unroll
    for (int j = 0; j < 8; j++)
        xs[((long)b * N + n0 + nb + j) * 64 + f] = acc[j];
}

// ---------- l2 normalize slice per b over N*64 = 16384 elems, in place ----------
__global__ void l2norm_slice(float* __restrict__ xs) {
    __shared__ float red[256];
    long base = (long)blockIdx.x * 16384;
    int tid = threadIdx.x;
    float s = 0.f;
    for (int i = tid; i < 16384; i += 256) { float v = xs[base + i]; s += v * v; }
    red[tid] = s; __syncthreads();
    for (int k = 128; k > 0; k >>= 1) {
        if (tid < k) red[tid] += red[tid + k];
        __syncthreads();
    }
    float scale = rsqrtf(fmaxf(red[0], 1e-12f));
    for (int i = tid; i < 16384; i += 256) xs[base + i] *= scale;
}

// ---------- LSTM1 step: F=64, Cin=64, fused input+recurrent conv ----------
__global__ __launch_bounds__(256)
void lstm1_step(const float* __restrict__ xs, const float* __restrict__ hprev,
                float* __restrict__ hcur, float* __restrict__ c1,
                const float* __restrict__ kx, const float* __restrict__ kh,
                const float* __restrict__ bias, int t) {
    __shared__ float sx[34 * 64];
    __shared__ float sh[34 * 64];
    int b = blockIdx.y, n0 = blockIdx.x * 32, tid = threadIdx.x;
    const float* xt = xs + (long)b * N * 64;
    const float* hp = hprev + (long)b * N * 64;
    for (int i = tid; i < 34 * 64; i += 256) {
        int p = i >> 6, c = i & 63;
        int nn = n0 + p - 1;
        bool ok = (nn >= 0 && nn < N);
        sx[i] = ok ? xt[nn * 64 + c] : 0.f;
        sh[i] = (ok && t > 0) ? hp[nn * 64 + c] : 0.f;
    }
    __syncthreads();
    int f = tid & 63, ng = tid >> 6;
    int nb = ng * 8;
    float bi = bias[f], bff = bias[64 + f], bc = bias[128 + f], bo = bias[192 + f];
    float gi[8], gf[8], gc[8], go[8];
#pragma unroll
    for (int j = 0; j < 8; j++) { gi[j] = bi; gf[j] = bff; gc[j] = bc; go[j] = bo; }
    for (int kn = 0; kn < 3; kn++)
        for (int c = 0; c < 64; c++) {
            int wi = (kn * 64 + c) * 256 + f;
            float xwi = kx[wi], xwf = kx[wi + 64], xwc = kx[wi + 128], xwo = kx[wi + 192];
            float hwi = kh[wi], hwf = kh[wi + 64], hwc = kh[wi + 128], hwo = kh[wi + 192];
            int pb = (nb + kn) * 64 + c;
#pragma unroll
            for (int j = 0; j < 8; j++) {
                float xv = sx[pb + j * 64];
                float hv = sh[pb + j * 64];
                gi[j] += xwi * xv + hwi * hv;
                gf[j] += xwf * xv + hwf * hv;
                gc[j] += xwc * xv + hwc * hv;
                go[j] += xwo * xv + hwo * hv;
            }
        }
    float* hout = hcur + (long)b * N * 64;
#pragma unroll
    for (int j = 0; j < 8; j++) {
        int n = n0 + nb + j;
        long ci = ((long)b * N + n) * 64 + f;
        float cp = (t > 0) ? c1[ci] : 0.f;
        float iv = hsig(gi[j]), fv = hsig(gf[j]), ov = hsig(go[j]);
        float cn = fv * cp + iv * tanhf(gc[j]);
        c1[ci] = cn;
        hout[n * 64 + f] = ov * tanhf(cn);
    }
}

// ---------- LSTM2 step: F=128, Cin=64 ----------
__global__ __launch_bounds__(256)
void lstm2_step(const float* __restrict__ h1cur, const float* __restrict__ hprev,
                float* __restrict__ hnext, float* __restrict__ c2,
                const float* __restrict__ kx, const float* __restrict__ kh,
                const float* __restrict__ bias, int t) {
    __shared__ float sx[18 * 64];
    __shared__ float sh[18 * 128];
    int b = blockIdx.y, n0 = blockIdx.x * 16, tid = threadIdx.x;
    const float* xt = h1cur + (long)b * N * 64;
    for (int i = tid; i < 18 * 64; i += 256) {
        int p = i >> 6, c = i & 63;
        int nn = n0 + p - 1;
        sx[i] = (nn >= 0 && nn < N) ? xt[nn * 64 + c] : 0.f;
    }
    for (int i = tid; i < 18 * 128; i += 256) {
        int p = i >> 7, c = i & 127;
        int nn = n0 + p - 1;
        sh[i] = (nn >= 0 && nn < N && t > 0) ? hprev[((long)b * N + nn) * 128 + c] : 0.f;
    }
    __syncthreads();
    int f = tid & 127, ng = tid >> 7;
    int nb = ng * 8;
    float gi[8], gf[8], gc[8], go[8];
    float bi = bias[f], bff = bias[128 + f], bc = bias[256 + f], bo = bias[384 + f];
#pragma unroll
    for (int j = 0; j < 8; j++) { gi[j] = bi; gf[j] = bff; gc[j] = bc; go[j] = bo; }
    for (int kn = 0; kn < 3; kn++)
        for (int c = 0; c < 64; c++) {
            int wi = (kn * 64 + c) * 512 + f;
            float wiv = kx[wi], wfv = kx[wi + 128], wcv = kx[wi + 256], wov = kx[wi + 384];
            int pb = (nb + kn) * 64 + c;
#pragma unroll
            for (int j = 0; j < 8; j++) {
                float xv = sx[pb + j * 64];
                gi[j] += wiv * xv; gf[j] += wfv * xv;
                gc[j] += wcv * xv; go[j] += wov * xv;
            }
        }
    for (int kn = 0; kn < 3; kn++)
        for (int c = 0; c < 128; c++) {
            int wi = (kn * 128 + c) * 512 + f;
            float wiv = kh[wi], wfv = kh[wi + 128], wcv = kh[wi + 256], wov = kh[wi + 384];
            int pb = (nb + kn) * 128 + c;
#pragma unroll
            for (int j = 0; j < 8; j++) {
                float hv = sh[pb + j * 128];
                gi[j] += wiv * hv; gf[j] += wfv * hv;
                gc[j] += wcv * hv; go[j] += wov * hv;
            }
        }
#pragma unroll
    for (int j = 0; j < 8; j++) {
        int n = n0 + nb + j;
        long ci = ((long)b * N + n) * 128 + f;
        float cp = (t > 0) ? c2[ci] : 0.f;
        float iv = hsig(gi[j]), fv = hsig(gf[j]), ov = hsig(go[j]);
        float cn = fv * cp + iv * tanhf(gc[j]);
        c2[ci] = cn;
        hnext[ci] = ov * tanhf(cn);
    }
}

// ---------- final: l2norm per b over N*F2, project 128->1, dtype-flagged store ----------
__global__ void final_kernel(const float* __restrict__ hT, const float* __restrict__ fcw,
                             const float* __restrict__ fcb, void* __restrict__ out,
                             const int* __restrict__ flag) {
    __shared__ float red[256];
    int b = blockIdx.x, tid = threadIdx.x;
    const float* hb = hT + (long)b * N * 128;
    float s = 0.f;
    for (int i = tid; i < N * 128; i += 256) { float v = hb[i]; s += v * v; }
    red[tid] = s; __syncthreads();
    for (int k = 128; k > 0; k >>= 1) {
        if (tid < k) red[tid] += red[tid + k];
        __syncthreads();
    }
    float scale = rsqrtf(fmaxf(red[0], 1e-12f));
    int n = tid;
    float acc = fcb[0];
    for (int c = 0; c < 128; c++) acc += hb[n * 128 + c] * scale * fcw[c];
    if (*flag) ((bf16*)out)[b * N + n] = __float2bfloat16(acc);
    else       ((float*)out)[b * N + n] = acc;
}

extern "C" void kernel_launch(void* const* d_in, const int* in_sizes, int n_in,
                              void* d_out, int out_size, void* d_ws, size_t ws_size,
                              hipStream_t stream) {
    // workspace layout (floats) — total ~11.32M floats = 45.3 MB
    float* ws   = (float*)d_ws;
    float* xs   = ws;                    // 1,048,576  (B*N*64 slice)
    float* h1A  = ws + 1048576;          // 1,048,576
    float* h1B  = ws + 2097152;          // 1,048,576
    float* c1   = ws + 3145728;          // 1,048,576
    float* h2A  = ws + 4194304;          // 2,097,152
    float* h2B  = ws + 6291456;          // 2,097,152
    float* c2   = ws + 8388608;          // 2,097,152
    float* xf   = ws + 10485760;         // 393,216 (B*T*N input as f32)
    float* w1c  = ws + 10878976;         // 576
    float* w2c  = ws + 10879552;         // 36,864
    float* kx1c = ws + 10916416;         // 49,152
    float* kh1c = ws + 10965568;         // 49,152
    float* kx2c = ws + 11014720;         // 98,304
    float* kh2c = ws + 11113024;         // 196,608
    float* bb1  = ws + 11309632;         // 64
    float* bb2  = ws + 11309696;         // 64
    float* bg1  = ws + 11309760;         // 256
    float* bg2  = ws + 11310016;         // 512
    float* fcwf = ws + 11310528;         // 128
    float* fcbf = ws + 11310656;         // 1
    int*   flag = (int*)(ws + 11310657); // 1

    detect_kernel<<<1, 256, 0, stream>>>((const unsigned short*)d_in[0], flag);

    struct { int idx; float* dst; int n; } cv[] = {
        {0, xf,   B * T * N}, {1, w1c, 576},   {2, bb1, 64},
        {3, w2c, 36864},      {4, bb2, 64},
        {5, kx1c, 49152},     {6, kh1c, 49152}, {7, bg1, 256},
        {8, kx2c, 98304},     {9, kh2c, 196608},{10, bg2, 512},
        {11, fcwf, 128},      {12, fcbf, 1},
    };
    for (auto& c : cv)
        cvt_any<<<(c.n + 255) / 256, 256, 0, stream>>>(d_in[c.idx], c.dst, c.n, flag);

    for (int t = 0; t < T; t++) {
        conv_slice_kernel<<<dim3(8, B), 256, 0, stream>>>(xf, w1c, bb1, w2c, bb2, xs, t);
        l2norm_slice<<<B, 256, 0, stream>>>(xs);
        const float* h1p = (t & 1) ? h1A : h1B;   // unused at t=0 (guarded)
        float* h1n = (t & 1) ? h1B : h1A;
        lstm1_step<<<dim3(8, B), 256, 0, stream>>>(xs, h1p, h1n, c1, kx1c, kh1c, bg1, t);
        const float* h2p = (t & 1) ? h2A : h2B;   // unused at t=0 (guarded)
        float* h2n = (t & 1) ? h2B : h2A;
        lstm2_step<<<dim3(16, B), 256, 0, stream>>>(h1n, h2p, h2n, c2, kx2c, kh2c, bg2, t);
    }
    // t=23 (odd) wrote h2B
    final_kernel<<<B, 256, 0, stream>>>(h2B, fcwf, fcbf, d_out, flag);
}

// Round 4
// 3305.351 us; speedup vs baseline: 2.2738x; 2.2738x over previous
//
#include <hip/hip_runtime.h>
#include <hip/hip_bf16.h>

using bf16 = __hip_bfloat16;
typedef unsigned short u16;
typedef unsigned int u32;
typedef __attribute__((ext_vector_type(8))) short short8;
typedef __attribute__((ext_vector_type(4))) float floatx4;

#define DEVI __device__ __forceinline__

constexpr int B = 64, T = 24, N = 256, F1 = 64, F2 = 128;

DEVI float b2f(bf16 v) { return __bfloat162float(v); }
DEVI float b2fu(u16 u) { return __uint_as_float(((u32)u) << 16); }
DEVI u16 f2b(float f) {                 // RNE float->bf16 bits
    u32 u = __float_as_uint(f);
    u32 r = (u + 0x7FFF + ((u >> 16) & 1)) >> 16;
    return (u16)r;
}
DEVI float hsig(float x) { x = x * 0.2f + 0.5f; return fminf(fmaxf(x, 0.f), 1.f); }

// async global->LDS 16B (per-lane source, lane-contiguous LDS dest)
#if __has_builtin(__builtin_amdgcn_global_load_lds)
#define ASYNC16(gsrc, ldst)                                                            \
    __builtin_amdgcn_global_load_lds((const __attribute__((address_space(1))) u32*)(gsrc), \
                                     (__attribute__((address_space(3))) u32*)(ldst), 16, 0, 0)
#define HAVE_ASYNC 1
#else
#define HAVE_ASYNC 0
#endif

// ---------- dtype detection: bf16 NaN/Inf patterns in first 65536 u16 of x ----------
__global__ void detect_kernel(const u16* __restrict__ xu, int* __restrict__ flag) {
    __shared__ int red[256];
    int tid = threadIdx.x;
    int cnt = 0;
    for (int i = tid; i < 65536; i += 256)
        if (((xu[i] >> 7) & 0xFF) == 0xFF) cnt++;
    red[tid] = cnt; __syncthreads();
    for (int k = 128; k > 0; k >>= 1) {
        if (tid < k) red[tid] += red[tid + k];
        __syncthreads();
    }
    if (tid == 0) *flag = (red[0] == 0) ? 1 : 0;
}

DEVI float read_in(const void* p, long i, int isbf) {
    return isbf ? b2f(((const bf16*)p)[i]) : ((const float*)p)[i];
}

// ---------- universal input -> f32 conversion ----------
__global__ void cvt_any(const void* __restrict__ s, float* __restrict__ d, int n,
                        const int* __restrict__ flag) {
    int i = blockIdx.x * 256 + threadIdx.x;
    if (i >= n) return;
    d[i] = read_in(s, i, *flag);
}

// ---------- weight repack: Wt[g][k] bf16, k = kn*(CIN+F) + c ; c<CIN -> kx, else kh ----------
__global__ void repack_w(const void* __restrict__ kxr, const void* __restrict__ khr,
                         u16* __restrict__ Wt, int CIN, int F, const int* __restrict__ flag) {
    int NG = 4 * F, CH = CIN + F, K = 3 * CH;
    int idx = blockIdx.x * 256 + threadIdx.x;
    if (idx >= NG * K) return;
    int g = idx / K, k = idx - g * K;
    int kn = k / CH, c = k - kn * CH;
    int isbf = *flag;
    float v = (c < CIN) ? read_in(kxr, (long)(kn * CIN + c) * NG + g, isbf)
                        : read_in(khr, (long)(kn * F + (c - CIN)) * NG + g, isbf);
    Wt[(long)g * K + k] = f2b(v);
}

// ---------- per-t slice: conv1(3x3,1->64) fused into conv2(3x3,64->64), fp32 ----------
__global__ __launch_bounds__(256)
void conv_slice_kernel(const float* __restrict__ x, const float* __restrict__ w1c,
                       const float* __restrict__ b1v, const float* __restrict__ w2c,
                       const float* __restrict__ b2v, float* __restrict__ xs, int t) {
    __shared__ float s1[3 * 34 * 64];
    __shared__ float sxw[5 * 36];
    int b = blockIdx.y, n0 = blockIdx.x * 32, tid = threadIdx.x;
    for (int i = tid; i < 180; i += 256) {
        int r = i / 36, cc = i - r * 36;
        int tt = t - 2 + r, nn = n0 - 2 + cc;
        float v = 0.f;
        if (tt >= 0 && tt < T && nn >= 0 && nn < N) v = x[(b * T + tt) * N + nn];
        sxw[i] = v;
    }
    __syncthreads();
    for (int i = tid; i < 3 * 34 * 64; i += 256) {
        int c = i & 63, qq = i >> 6;
        int tti = qq / 34, p = qq - tti * 34;
        int tt = t - 1 + tti, nn = n0 + p - 1;
        float v = 0.f;
        if (tt >= 0 && tt < T && nn >= 0 && nn < N) {
            v = b1v[c];
            for (int dt = 0; dt < 3; dt++)
#pragma unroll
                for (int dn = 0; dn < 3; dn++)
                    v += sxw[(tti + dt) * 36 + (p + dn)] * w1c[(dt * 3 + dn) * 64 + c];
        }
        s1[i] = v;
    }
    __syncthreads();
    int f = tid & 63, ng = tid >> 6;
    int nb = ng * 8;
    float bv = b2v[f];
    float acc[8];
#pragma unroll
    for (int j = 0; j < 8; j++) acc[j] = bv;
    for (int kt = 0; kt < 3; kt++)
        for (int kn = 0; kn < 3; kn++)
            for (int c = 0; c < 64; c++) {
                float w = w2c[((kt * 3 + kn) * 64 + c) * 64 + f];
                int base = (kt * 34 + nb + kn) * 64 + c;
#pragma unroll
                for (int j = 0; j < 8; j++) acc[j] += w * s1[base + j * 64];
            }
#pragma unroll
    for (int j = 0; j < 8; j++)
        xs[((long)b * N + n0 + nb + j) * 64 + f] = acc[j];
}

// ---------- l2 normalize slice per b over N*64, fp32 in -> bf16 out ----------
__global__ void l2norm_slice(const float* __restrict__ xsf, u16* __restrict__ xs) {
    __shared__ float red[256];
    long base = (long)blockIdx.x * 16384;
    int tid = threadIdx.x;
    float s = 0.f;
    for (int i = tid; i < 16384; i += 256) { float v = xsf[base + i]; s += v * v; }
    red[tid] = s; __syncthreads();
    for (int k = 128; k > 0; k >>= 1) {
        if (tid < k) red[tid] += red[tid + k];
        __syncthreads();
    }
    float scale = rsqrtf(fmaxf(red[0], 1e-12f));
    for (int i = tid; i < 16384; i += 256) xs[base + i] = f2b(xsf[base + i] * scale);
}

// ---------- MFMA ConvLSTM step ----------
// Block: 256 thr = 4 waves. Tile: M=64 n-positions x NG=4F gates; wave w = gate type w (F cols).
// A = LDS halo window [66 rows][CIN+F ch] bf16 (padded stride). B = Wt[g][k] bf16 streamed
// per-32-k chunk via double-buffered global_load_lds with XOR-swizzled 16B units.
template<int CIN, int F>
__global__ __launch_bounds__(256, 1)
void lstm_mfma(const u16* __restrict__ xin, const u16* __restrict__ hprev,
               u16* __restrict__ hnext, float* __restrict__ cst,
               const u16* __restrict__ Wt, const float* __restrict__ bias, int t) {
    constexpr int CH = CIN + F;          // channels per tap (128 / 192)
    constexpr int CHP = CH + 8;          // padded window stride (136 / 200) -> 2-way banks
    constexpr int K = 3 * CH;            // 384 / 576
    constexpr int NK = K / 32;           // 12 / 18
    constexpr int NG = 4 * F;            // 256 / 512
    constexpr int NGP = NG + 4;
    constexpr int NI = F / 16;           // 4 / 8 col-frags per wave
    constexpr int BCH = NG * 32;         // ushorts per B chunk buffer
    constexpr int GLD_USH = 32 * NGP * 2;
    constexpr int UNION_USH = (2 * BCH > GLD_USH) ? 2 * BCH : GLD_USH;
    constexpr int LOGF = (F == 128) ? 7 : 6;

    __shared__ __align__(16) u16 win[66 * CHP];
    __shared__ __align__(16) u16 ubuf[UNION_USH];   // B chunks during K-loop; Gld in epilogue
    u16* bch = ubuf;
    float* Gld = (float*)ubuf;

    int tid = threadIdx.x;
    int bb = blockIdx.y, n0 = blockIdx.x * 64;
    int w = tid >> 6, l15 = tid & 15, q = (tid >> 4) & 3;

    // ---- fill A window: row = n0-1+r, ch<CIN from xin, ch>=CIN from hprev (0 at t==0) ----
    constexpr int GRP = CH / 4;
    for (int i = tid; i < 66 * GRP; i += 256) {
        int row = i / GRP, g4 = (i - row * GRP) * 4;
        int n = n0 + row - 1;
        uint2 v{};
        if (n >= 0 && n < N) {
            if (g4 < CIN) v = *(const uint2*)&xin[((long)bb * N + n) * CIN + g4];
            else if (t > 0) v = *(const uint2*)&hprev[((long)bb * N + n) * F + (g4 - CIN)];
        }
        *(uint2*)&win[row * CHP + g4] = v;
    }

    // ---- stage B chunk kk into buffer bufi (16B units, XOR swizzle u^(g&3)) ----
    auto stage = [&](int kk, int bufi) {
        int kbase = kk * 32;
#pragma unroll
        for (int it = 0; it < NG / 64; ++it) {
            int P = it * 256 + tid;
            int g = P >> 2, u = P & 3;
            int k = kbase + ((u ^ (g & 3)) << 3);
#if HAVE_ASYNC
            ASYNC16(Wt + (long)g * K + k, &bch[bufi * BCH + P * 8]);
#else
            uint4 v = *(const uint4*)(Wt + (long)g * K + k);
            *(uint4*)&bch[bufi * BCH + P * 8] = v;
#endif
        }
    };

    stage(0, 0);
    __syncthreads();

    floatx4 acc[4][NI] = {};

    for (int kk = 0; kk < NK; ++kk) {
        int cur = kk & 1;
        if (kk + 1 < NK) stage(kk + 1, 1 - cur);
        int kbase = kk * 32;
        int kn = kbase / CH, c0 = kbase - kn * CH;
        short8 af[4];
#pragma unroll
        for (int mi = 0; mi < 4; mi++)
            af[mi] = *(const short8*)&win[(mi * 16 + l15 + kn) * CHP + c0 + q * 8];
#pragma unroll
        for (int ni = 0; ni < NI; ni++) {
            int g = w * F + ni * 16 + l15;
            short8 bf = *(const short8*)&bch[cur * BCH + g * 32 + ((q ^ (g & 3)) << 3)];
#pragma unroll
            for (int mi = 0; mi < 4; mi++)
                acc[mi][ni] = __builtin_amdgcn_mfma_f32_16x16x32_bf16(af[mi], bf, acc[mi][ni], 0, 0, 0);
        }
        __syncthreads();   // drains prefetch (vmcnt0) + guards buffer reuse
    }

    // ---- epilogue in 2 halves of 32 m-rows: exchange gates via LDS, fused LSTM update ----
    for (int h = 0; h < 2; ++h) {
#pragma unroll
        for (int mi2 = 0; mi2 < 2; ++mi2) {
            int mi = h * 2 + mi2;
#pragma unroll
            for (int ni = 0; ni < NI; ni++)
#pragma unroll
                for (int r = 0; r < 4; r++)
                    Gld[(mi2 * 16 + q * 4 + r) * NGP + w * F + ni * 16 + l15] = acc[mi][ni][r];
        }
        __syncthreads();
        for (int i = tid; i < 32 * F; i += 256) {
            int m = i >> LOGF, f = i & (F - 1);
            float gi = Gld[m * NGP + f]         + bias[f];
            float gf = Gld[m * NGP + F + f]     + bias[F + f];
            float gc = Gld[m * NGP + 2 * F + f] + bias[2 * F + f];
            float go = Gld[m * NGP + 3 * F + f] + bias[3 * F + f];
            int n = n0 + h * 32 + m;
            long ci = ((long)bb * N + n) * F + f;
            float cp = (t > 0) ? cst[ci] : 0.f;
            float iv = hsig(gi), fv = hsig(gf), ov = hsig(go);
            float cn = fv * cp + iv * tanhf(gc);
            cst[ci] = cn;
            hnext[ci] = f2b(ov * tanhf(cn));
        }
        __syncthreads();
    }
}

// ---------- final: l2norm per b over N*F2 (bf16 in), project 128->1, flag-dtype store ----------
__global__ void final_kernel(const u16* __restrict__ hT, const float* __restrict__ fcw,
                             const float* __restrict__ fcb, void* __restrict__ out,
                             const int* __restrict__ flag) {
    __shared__ float red[256];
    int b = blockIdx.x, tid = threadIdx.x;
    const u16* hb = hT + (long)b * N * 128;
    float s = 0.f;
    for (int i = tid; i < N * 128; i += 256) { float v = b2fu(hb[i]); s += v * v; }
    red[tid] = s; __syncthreads();
    for (int k = 128; k > 0; k >>= 1) {
        if (tid < k) red[tid] += red[tid + k];
        __syncthreads();
    }
    float scale = rsqrtf(fmaxf(red[0], 1e-12f));
    int n = tid;
    float acc = fcb[0];
    for (int c = 0; c < 128; c++) acc += b2fu(hb[n * 128 + c]) * scale * fcw[c];
    if (*flag) ((bf16*)out)[b * N + n] = __float2bfloat16(acc);
    else       ((float*)out)[b * N + n] = acc;
}

extern "C" void kernel_launch(void* const* d_in, const int* in_sizes, int n_in,
                              void* d_out, int out_size, void* d_ws, size_t ws_size,
                              hipStream_t stream) {
    float* ws = (float*)d_ws;
    // fp32 buffers
    float* xsf  = ws;                     // 1,048,576 (conv2 out slice)
    float* c1   = ws + 1048576;           // 1,048,576
    float* c2   = ws + 2097152;           // 2,097,152
    // bf16 buffers (u16), sizes in float units
    u16* xs_bf  = (u16*)(ws + 4194304);   // 524,288 fl  (B*N*64)
    u16* h1A    = (u16*)(ws + 4718592);   // 524,288
    u16* h1B    = (u16*)(ws + 5242880);   // 524,288
    u16* h2A    = (u16*)(ws + 5767168);   // 1,048,576 (B*N*128)
    u16* h2B    = (u16*)(ws + 6815744);   // 1,048,576
    u16* Wt1    = (u16*)(ws + 7864320);   // 49,152  (256x384)
    u16* Wt2    = (u16*)(ws + 7913472);   // 147,456 (512x576)
    float* w2c  = ws + 8060928;           // 36,864
    float* xf   = ws + 8097792;           // 393,216
    float* w1c  = ws + 8491008;           // 576
    float* bb1  = ws + 8491584;           // 64
    float* bb2  = ws + 8491648;           // 64
    float* bg1  = ws + 8491712;           // 256
    float* bg2  = ws + 8491968;           // 512
    float* fcwf = ws + 8492480;           // 128
    float* fcbf = ws + 8492608;           // 1
    int*   flag = (int*)(ws + 8492612);   // total ~8.49M fl = 34 MB

    detect_kernel<<<1, 256, 0, stream>>>((const u16*)d_in[0], flag);

    struct { int idx; float* dst; int n; } cv[] = {
        {0, xf, B * T * N}, {1, w1c, 576}, {2, bb1, 64}, {3, w2c, 36864}, {4, bb2, 64},
        {7, bg1, 256}, {10, bg2, 512}, {11, fcwf, 128}, {12, fcbf, 1},
    };
    for (auto& c : cv)
        cvt_any<<<(c.n + 255) / 256, 256, 0, stream>>>(d_in[c.idx], c.dst, c.n, flag);

    repack_w<<<(256 * 384 + 255) / 256, 256, 0, stream>>>(d_in[5], d_in[6], Wt1, 64, 64, flag);
    repack_w<<<(512 * 576 + 255) / 256, 256, 0, stream>>>(d_in[8], d_in[9], Wt2, 64, 128, flag);

    for (int t = 0; t < T; t++) {
        conv_slice_kernel<<<dim3(8, B), 256, 0, stream>>>(xf, w1c, bb1, w2c, bb2, xsf, t);
        l2norm_slice<<<B, 256, 0, stream>>>(xsf, xs_bf);
        const u16* h1p = (t & 1) ? h1A : h1B;
        u16* h1n = (t & 1) ? h1B : h1A;
        lstm_mfma<64, 64><<<dim3(4, B), 256, 0, stream>>>(xs_bf, h1p, h1n, c1, Wt1, bg1, t);
        const u16* h2p = (t & 1) ? h2A : h2B;
        u16* h2n = (t & 1) ? h2B : h2A;
        lstm_mfma<64, 128><<<dim3(4, B), 256, 0, stream>>>(h1n, h2p, h2n, c2, Wt2, bg2, t);
    }
    final_kernel<<<B, 256, 0, stream>>>(h2B, fcwf, fcbf, d_out, flag);
}

// Round 5
// 1659.925 us; speedup vs baseline: 4.5277x; 1.9913x over previous
//
#include <hip/hip_runtime.h>
#include <hip/hip_bf16.h>

using bf16 = __hip_bfloat16;
typedef unsigned short u16;
typedef unsigned int u32;
typedef __attribute__((ext_vector_type(8))) short short8;
typedef __attribute__((ext_vector_type(4))) float floatx4;

#define DEVI __device__ __forceinline__

constexpr int B = 64, T = 24, N = 256, F1 = 64, F2 = 128;
constexpr int GG = 6;                    // timesteps per conv group

DEVI float b2f(bf16 v) { return __bfloat162float(v); }
DEVI float b2fu(u16 u) { return __uint_as_float(((u32)u) << 16); }
DEVI u16 f2b(float f) {                  // RNE float->bf16 bits
    u32 u = __float_as_uint(f);
    u32 r = (u + 0x7FFF + ((u >> 16) & 1)) >> 16;
    return (u16)r;
}
DEVI float hsig(float x) { x = x * 0.2f + 0.5f; return fminf(fmaxf(x, 0.f), 1.f); }

#if __has_builtin(__builtin_amdgcn_global_load_lds)
#define ASYNC16(gsrc, ldst)                                                            \
    __builtin_amdgcn_global_load_lds((const __attribute__((address_space(1))) u32*)(gsrc), \
                                     (__attribute__((address_space(3))) u32*)(ldst), 16, 0, 0)
#define HAVE_ASYNC 1
#else
#define HAVE_ASYNC 0
#endif

DEVI float read_in(const void* p, long i, int isbf) {
    return isbf ? b2f(((const bf16*)p)[i]) : ((const float*)p)[i];
}

// ---------- dtype detection ----------
__global__ void init_flag(int* flag) { *flag = 1; }
__global__ void detect_scan(const u16* __restrict__ xu, int* __restrict__ flag) {
    int i0 = blockIdx.x * 2048 + threadIdx.x;
    int hit = 0;
    for (int i = i0; i < (blockIdx.x + 1) * 2048; i += 256)
        if (((xu[i] >> 7) & 0xFF) == 0xFF) hit = 1;   // bf16 exp all-ones never occurs for N(0,1) bf16
    if (hit) *flag = 0;                               // fp32 reinterpreted as u16 -> expect ~256 hits
}

// ---------- fused setup: convert small tensors to f32 (src=nullptr -> zero-fill) ----------
struct CvtDesc { const void* src; float* dst; int n; };
struct CvtPack { CvtDesc d[8]; };
__global__ void cvt_pack(CvtPack p, const int* __restrict__ flag) {
    CvtDesc c = p.d[blockIdx.x];
    int isbf = *flag;
    for (int i = threadIdx.x; i < c.n; i += 256)
        c.dst[i] = c.src ? read_in(c.src, i, isbf) : 0.f;
}

// ---------- LSTM weight repack: Wt[g][k], k = kn*(CIN+F)+c ; c<CIN -> kx else kh ----------
__global__ void repack_w(const void* __restrict__ kxr, const void* __restrict__ khr,
                         u16* __restrict__ Wt, int CIN, int F, const int* __restrict__ flag) {
    int NG = 4 * F, CH = CIN + F, K = 3 * CH;
    int idx = blockIdx.x * 256 + threadIdx.x;
    if (idx >= NG * K) return;
    int g = idx / K, k = idx - g * K;
    int kn = k / CH, c = k - kn * CH;
    int isbf = *flag;
    float v = (c < CIN) ? read_in(kxr, (long)(kn * CIN + c) * NG + g, isbf)
                        : read_in(khr, (long)(kn * F + (c - CIN)) * NG + g, isbf);
    Wt[(long)g * K + k] = f2b(v);
}

// ---------- conv2 weight repack: w2b[f][k], k = kt*192 + kn*64 + c ; w2 is HWIO (3,3,64,64) ----------
__global__ void repack_w2(const void* __restrict__ w2r, u16* __restrict__ w2b,
                          const int* __restrict__ flag) {
    int idx = blockIdx.x * 256 + threadIdx.x;
    if (idx >= 64 * 576) return;
    int f = idx / 576, k = idx - f * 576;
    int kt = k / 192, rem = k - kt * 192, kn = rem >> 6, c = rem & 63;
    float v = read_in(w2r, (long)((kt * 3 + kn) * 64 + c) * 64 + f, *flag);
    w2b[(long)f * 576 + k] = f2b(v);
}

// ---------- MFMA conv: conv1(on-the-fly) + conv2 as GEMM, 6 timesteps/dispatch ----------
// grid (4, B, GG); block 256 = 4 waves. Tile M=64 n-rows x 64 f-out. K = 3(kt)*3(kn)*64(c) = 576.
// Writes UNNORMALIZED bf16 + atomic per-(b,t) sumsq (l2norm folded into lstm1 A-load).
__global__ __launch_bounds__(256)
void conv_mfma(const void* __restrict__ xraw, const float* __restrict__ w1c,
               const float* __restrict__ b1v, const u16* __restrict__ w2b,
               const float* __restrict__ b2v, u16* __restrict__ xs6,
               float* __restrict__ ssq, const int* __restrict__ flag, int g0) {
    constexpr int CP1 = 72;                       // win1 row stride (u16)
    __shared__ __align__(16) u16 win1[3 * 66 * CP1];   // conv1 bf16: [kt][r1=nn-(n0-1)][c]
    __shared__ float sxw[5 * 68];                 // x window rows t-2..t+2, cols n0-2..n0+65
    __shared__ __align__(16) u16 bch[2 * 2048];   // B double buffer: 64 f x 32 k
    __shared__ float red[256];

    int tid = threadIdx.x;
    int bb = blockIdx.y, n0 = blockIdx.x * 64, t = g0 * GG + blockIdx.z;
    int w = tid >> 6, l15 = tid & 15, q = (tid >> 4) & 3;
    int isbf = *flag;

    for (int i = tid; i < 5 * 68; i += 256) {
        int r = i / 68, cc = i - r * 68;
        int tt = t - 2 + r, nn = n0 - 2 + cc;
        float v = 0.f;
        if (tt >= 0 && tt < T && nn >= 0 && nn < N)
            v = read_in(xraw, (long)(bb * T + tt) * N + nn, isbf);
        sxw[i] = v;
    }
    __syncthreads();
    // conv1 on the fly (zero outside valid (tt,nn) == conv2 SAME padding)
    for (int i = tid; i < 3 * 66 * 64; i += 256) {
        int c = i & 63, rr = i >> 6;
        int kt = rr / 66, r1 = rr - kt * 66;
        int tt = t - 1 + kt, nn = n0 - 1 + r1;
        u16 o = 0;
        if (tt >= 0 && tt < T && nn >= 0 && nn < N) {
            float v = b1v[c];
            for (int dt = 0; dt < 3; dt++)
#pragma unroll
                for (int dn = 0; dn < 3; dn++)
                    v += sxw[(kt + dt) * 68 + r1 + dn] * w1c[(dt * 3 + dn) * 64 + c];
            o = f2b(v);
        }
        win1[(kt * 66 + r1) * CP1 + c] = o;
    }

    auto stage = [&](int kk, int bufi) {
        int g = tid >> 2, u = tid & 3;
        int k = kk * 32 + ((u ^ (g & 3)) << 3);
#if HAVE_ASYNC
        ASYNC16(w2b + (long)g * 576 + k, &bch[bufi * 2048 + tid * 8]);
#else
        uint4 v = *(const uint4*)(w2b + (long)g * 576 + k);
        *(uint4*)&bch[bufi * 2048 + tid * 8] = v;
#endif
    };
    stage(0, 0);
    __syncthreads();

    floatx4 acc[4] = {};
    for (int kk = 0; kk < 18; ++kk) {
        int cur = kk & 1;
        if (kk + 1 < 18) stage(kk + 1, 1 - cur);
        int kbase = kk * 32;
        int kt = kbase / 192, rem = kbase - kt * 192, kn = rem >> 6, c0 = rem & 63;
        int gcol = w * 16 + l15;
        short8 bf = *(const short8*)&bch[cur * 2048 + gcol * 32 + ((q ^ (gcol & 3)) << 3)];
#pragma unroll
        for (int mi = 0; mi < 4; mi++) {
            short8 af = *(const short8*)&win1[(kt * 66 + mi * 16 + l15 + kn) * CP1 + c0 + q * 8];
            acc[mi] = __builtin_amdgcn_mfma_f32_16x16x32_bf16(af, bf, acc[mi], 0, 0, 0);
        }
        __syncthreads();
    }

    // epilogue: add bias, write bf16 (unnormalized), accumulate sumsq
    u16* xslice = xs6 + (long)blockIdx.z * B * N * 64;
    int f = w * 16 + l15;
    float bias2 = b2v[f];
    float lsum = 0.f;
#pragma unroll
    for (int mi = 0; mi < 4; mi++)
#pragma unroll
        for (int r = 0; r < 4; r++) {
            int n = n0 + mi * 16 + q * 4 + r;
            float v = acc[mi][r] + bias2;
            lsum += v * v;
            xslice[((long)bb * N + n) * 64 + f] = f2b(v);
        }
    red[tid] = lsum; __syncthreads();
    for (int k = 128; k > 0; k >>= 1) {
        if (tid < k) red[tid] += red[tid + k];
        __syncthreads();
    }
    if (tid == 0) atomicAdd(&ssq[bb * T + t], red[0]);
}

// ---------- MFMA ConvLSTM step (as round 4) + optional folded l2norm scale on x ----------
template<int CIN, int F>
__global__ __launch_bounds__(256, 1)
void lstm_mfma(const u16* __restrict__ xin, const u16* __restrict__ hprev,
               u16* __restrict__ hnext, float* __restrict__ cst,
               const u16* __restrict__ Wt, const float* __restrict__ bias,
               const float* __restrict__ ssqp, int t) {
    constexpr int CH = CIN + F;
    constexpr int CHP = CH + 8;
    constexpr int K = 3 * CH;
    constexpr int NK = K / 32;
    constexpr int NG = 4 * F;
    constexpr int NGP = NG + 4;
    constexpr int NI = F / 16;
    constexpr int BCH = NG * 32;
    constexpr int GLD_USH = 32 * NGP * 2;
    constexpr int UNION_USH = (2 * BCH > GLD_USH) ? 2 * BCH : GLD_USH;
    constexpr int LOGF = (F == 128) ? 7 : 6;

    __shared__ __align__(16) u16 win[66 * CHP];
    __shared__ __align__(16) u16 ubuf[UNION_USH];
    u16* bch = ubuf;
    float* Gld = (float*)ubuf;

    int tid = threadIdx.x;
    int bb = blockIdx.y, n0 = blockIdx.x * 64;
    int w = tid >> 6, l15 = tid & 15, q = (tid >> 4) & 3;

    float scale = 1.f;
    if (ssqp) scale = rsqrtf(fmaxf(ssqp[bb * T + t], 1e-12f));

    constexpr int GRP = CH / 4;
    for (int i = tid; i < 66 * GRP; i += 256) {
        int row = i / GRP, g4 = (i - row * GRP) * 4;
        int n = n0 + row - 1;
        uint2 v{};
        if (n >= 0 && n < N) {
            if (g4 < CIN) {
                v = *(const uint2*)&xin[((long)bb * N + n) * CIN + g4];
                if (ssqp) {  // fold l2norm scale, re-round to bf16
                    u16 e0 = f2b(b2fu((u16)(v.x & 0xFFFF)) * scale);
                    u16 e1 = f2b(b2fu((u16)(v.x >> 16)) * scale);
                    u16 e2 = f2b(b2fu((u16)(v.y & 0xFFFF)) * scale);
                    u16 e3 = f2b(b2fu((u16)(v.y >> 16)) * scale);
                    v.x = (u32)e0 | ((u32)e1 << 16);
                    v.y = (u32)e2 | ((u32)e3 << 16);
                }
            } else if (t > 0) {
                v = *(const uint2*)&hprev[((long)bb * N + n) * F + (g4 - CIN)];
            }
        }
        *(uint2*)&win[row * CHP + g4] = v;
    }

    auto stage = [&](int kk, int bufi) {
        int kbase = kk * 32;
#pragma unroll
        for (int it = 0; it < NG / 64; ++it) {
            int P = it * 256 + tid;
            int g = P >> 2, u = P & 3;
            int k = kbase + ((u ^ (g & 3)) << 3);
#if HAVE_ASYNC
            ASYNC16(Wt + (long)g * K + k, &bch[bufi * BCH + P * 8]);
#else
            uint4 v = *(const uint4*)(Wt + (long)g * K + k);
            *(uint4*)&bch[bufi * BCH + P * 8] = v;
#endif
        }
    };
    stage(0, 0);
    __syncthreads();

    floatx4 acc[4][NI] = {};
    for (int kk = 0; kk < NK; ++kk) {
        int cur = kk & 1;
        if (kk + 1 < NK) stage(kk + 1, 1 - cur);
        int kbase = kk * 32;
        int kn = kbase / CH, c0 = kbase - kn * CH;
        short8 af[4];
#pragma unroll
        for (int mi = 0; mi < 4; mi++)
            af[mi] = *(const short8*)&win[(mi * 16 + l15 + kn) * CHP + c0 + q * 8];
#pragma unroll
        for (int ni = 0; ni < NI; ni++) {
            int g = w * F + ni * 16 + l15;
            short8 bf = *(const short8*)&bch[cur * BCH + g * 32 + ((q ^ (g & 3)) << 3)];
#pragma unroll
            for (int mi = 0; mi < 4; mi++)
                acc[mi][ni] = __builtin_amdgcn_mfma_f32_16x16x32_bf16(af[mi], bf, acc[mi][ni], 0, 0, 0);
        }
        __syncthreads();
    }

    for (int h = 0; h < 2; ++h) {
#pragma unroll
        for (int mi2 = 0; mi2 < 2; ++mi2) {
            int mi = h * 2 + mi2;
#pragma unroll
            for (int ni = 0; ni < NI; ni++)
#pragma unroll
                for (int r = 0; r < 4; r++)
                    Gld[(mi2 * 16 + q * 4 + r) * NGP + w * F + ni * 16 + l15] = acc[mi][ni][r];
        }
        __syncthreads();
        for (int i = tid; i < 32 * F; i += 256) {
            int m = i >> LOGF, f = i & (F - 1);
            float gi = Gld[m * NGP + f]         + bias[f];
            float gf = Gld[m * NGP + F + f]     + bias[F + f];
            float gc = Gld[m * NGP + 2 * F + f] + bias[2 * F + f];
            float go = Gld[m * NGP + 3 * F + f] + bias[3 * F + f];
            int n = n0 + h * 32 + m;
            long ci = ((long)bb * N + n) * F + f;
            float cp = (t > 0) ? cst[ci] : 0.f;
            float iv = hsig(gi), fv = hsig(gf), ov = hsig(go);
            float cn = fv * cp + iv * tanhf(gc);
            cst[ci] = cn;
            hnext[ci] = f2b(ov * tanhf(cn));
        }
        __syncthreads();
    }
}

// ---------- final: l2norm per b over N*F2 (bf16 in), project 128->1, flag-dtype store ----------
__global__ void final_kernel(const u16* __restrict__ hT, const float* __restrict__ fcw,
                             const float* __restrict__ fcb, void* __restrict__ out,
                             const int* __restrict__ flag) {
    __shared__ float red[256];
    int b = blockIdx.x, tid = threadIdx.x;
    const u16* hb = hT + (long)b * N * 128;
    float s = 0.f;
    for (int i = tid; i < N * 128; i += 256) { float v = b2fu(hb[i]); s += v * v; }
    red[tid] = s; __syncthreads();
    for (int k = 128; k > 0; k >>= 1) {
        if (tid < k) red[tid] += red[tid + k];
        __syncthreads();
    }
    float scale = rsqrtf(fmaxf(red[0], 1e-12f));
    int n = tid;
    float acc = fcb[0];
    for (int c = 0; c < 128; c++) acc += b2fu(hb[n * 128 + c]) * scale * fcw[c];
    if (*flag) ((bf16*)out)[b * N + n] = __float2bfloat16(acc);
    else       ((float*)out)[b * N + n] = acc;
}

extern "C" void kernel_launch(void* const* d_in, const int* in_sizes, int n_in,
                              void* d_out, int out_size, void* d_ws, size_t ws_size,
                              hipStream_t stream) {
    float* ws = (float*)d_ws;
    u16* xs6   = (u16*)ws;                 // GG*B*N*64 u16 = 3,145,728 fl
    u16* h1A   = (u16*)(ws + 3145728);     // 524,288 fl
    u16* h1B   = (u16*)(ws + 3670016);     // 524,288
    u16* h2A   = (u16*)(ws + 4194304);     // 1,048,576
    u16* h2B   = (u16*)(ws + 5242880);     // 1,048,576
    float* c1  = ws + 6291456;             // 1,048,576
    float* c2  = ws + 7340032;             // 2,097,152
    u16* Wt1   = (u16*)(ws + 9437184);     // 256x384 u16 = 49,152 fl
    u16* Wt2   = (u16*)(ws + 9486336);     // 512x576 u16 = 147,456 fl
    u16* w2b   = (u16*)(ws + 9633792);     // 64x576 u16 = 18,432 fl
    float* w1c  = ws + 9652224;            // 576
    float* bb1  = ws + 9652800;            // 64
    float* bb2  = ws + 9652864;            // 64
    float* bg1  = ws + 9652928;            // 256
    float* bg2  = ws + 9653184;            // 512
    float* fcwf = ws + 9653696;            // 128
    float* fcbf = ws + 9653824;            // 1
    float* ssq  = ws + 9653825;            // B*T = 1536
    int*   flag = (int*)(ws + 9655361);    // total ~9.66M fl = 38.6 MB

    init_flag<<<1, 1, 0, stream>>>(flag);
    detect_scan<<<32, 256, 0, stream>>>((const u16*)d_in[0], flag);

    CvtPack pk;
    pk.d[0] = {d_in[1],  w1c,  576};
    pk.d[1] = {d_in[2],  bb1,  64};
    pk.d[2] = {d_in[4],  bb2,  64};
    pk.d[3] = {d_in[7],  bg1,  256};
    pk.d[4] = {d_in[10], bg2,  512};
    pk.d[5] = {d_in[11], fcwf, 128};
    pk.d[6] = {d_in[12], fcbf, 1};
    pk.d[7] = {nullptr,  ssq,  B * T};     // zero-fill (poisoned 0xAA otherwise)
    cvt_pack<<<8, 256, 0, stream>>>(pk, flag);

    repack_w<<<(256 * 384 + 255) / 256, 256, 0, stream>>>(d_in[5], d_in[6], Wt1, 64, 64, flag);
    repack_w<<<(512 * 576 + 255) / 256, 256, 0, stream>>>(d_in[8], d_in[9], Wt2, 64, 128, flag);
    repack_w2<<<(64 * 576 + 255) / 256, 256, 0, stream>>>(d_in[3], w2b, flag);

    for (int g = 0; g < T / GG; g++) {
        conv_mfma<<<dim3(4, B, GG), 256, 0, stream>>>(d_in[0], w1c, bb1, w2b, bb2, xs6, ssq, flag, g);
        for (int ti = 0; ti < GG; ti++) {
            int t = g * GG + ti;
            const u16* h1p = (t & 1) ? h1A : h1B;
            u16* h1n = (t & 1) ? h1B : h1A;
            lstm_mfma<64, 64><<<dim3(4, B), 256, 0, stream>>>(
                xs6 + (long)ti * B * N * 64, h1p, h1n, c1, Wt1, bg1, ssq, t);
            const u16* h2p = (t & 1) ? h2A : h2B;
            u16* h2n = (t & 1) ? h2B : h2A;
            lstm_mfma<64, 128><<<dim3(4, B), 256, 0, stream>>>(
                h1n, h2p, h2n, c2, Wt2, bg2, nullptr, t);
        }
    }
    final_kernel<<<B, 256, 0, stream>>>(h2B, fcwf, fcbf, d_out, flag);
}

// Round 6
// 1055.827 us; speedup vs baseline: 7.1182x; 1.5722x over previous
//
#include <hip/hip_runtime.h>
#include <hip/hip_bf16.h>

using bf16 = __hip_bfloat16;
typedef unsigned short u16;
typedef unsigned int u32;
typedef __attribute__((ext_vector_type(8))) short short8;
typedef __attribute__((ext_vector_type(4))) float floatx4;

#define DEVI __device__ __forceinline__

constexpr int B = 64, T = 24, N = 256, F1 = 64, F2 = 128;
constexpr int GG = 6;                    // timesteps per conv group

DEVI float b2f(bf16 v) { return __bfloat162float(v); }
DEVI float b2fu(u16 u) { return __uint_as_float(((u32)u) << 16); }
DEVI u16 f2b(float f) {                  // RNE float->bf16 bits
    u32 u = __float_as_uint(f);
    u32 r = (u + 0x7FFF + ((u >> 16) & 1)) >> 16;
    return (u16)r;
}
DEVI float hsig(float x) { x = x * 0.2f + 0.5f; return fminf(fmaxf(x, 0.f), 1.f); }

#if __has_builtin(__builtin_amdgcn_global_load_lds)
#define ASYNC16(gsrc, ldst)                                                            \
    __builtin_amdgcn_global_load_lds((const __attribute__((address_space(1))) u32*)(gsrc), \
                                     (__attribute__((address_space(3))) u32*)(ldst), 16, 0, 0)
#define HAVE_ASYNC 1
#else
#define HAVE_ASYNC 0
#endif

DEVI float read_in(const void* p, long i, int isbf) {
    return isbf ? b2f(((const bf16*)p)[i]) : ((const float*)p)[i];
}

// ---------- dtype detection ----------
__global__ void init_flag(int* flag) { *flag = 1; }
__global__ void detect_scan(const u16* __restrict__ xu, int* __restrict__ flag) {
    int i0 = blockIdx.x * 2048 + threadIdx.x;
    int hit = 0;
    for (int i = i0; i < (blockIdx.x + 1) * 2048; i += 256)
        if (((xu[i] >> 7) & 0xFF) == 0xFF) hit = 1;
    if (hit) *flag = 0;
}

// ---------- fused setup: convert small tensors to f32 (src=nullptr -> zero-fill) ----------
struct CvtDesc { const void* src; float* dst; int n; };
struct CvtPack { CvtDesc d[8]; };
__global__ void cvt_pack(CvtPack p, const int* __restrict__ flag) {
    CvtDesc c = p.d[blockIdx.x];
    int isbf = *flag;
    for (int i = threadIdx.x; i < c.n; i += 256)
        c.dst[i] = c.src ? read_in(c.src, i, isbf) : 0.f;
}

// ---------- LSTM weight repack: Wt[g][k], k = kn*(CIN+F)+c ; c<CIN -> kx else kh ----------
__global__ void repack_w(const void* __restrict__ kxr, const void* __restrict__ khr,
                         u16* __restrict__ Wt, int CIN, int F, const int* __restrict__ flag) {
    int NG = 4 * F, CH = CIN + F, K = 3 * CH;
    int idx = blockIdx.x * 256 + threadIdx.x;
    if (idx >= NG * K) return;
    int g = idx / K, k = idx - g * K;
    int kn = k / CH, c = k - kn * CH;
    int isbf = *flag;
    float v = (c < CIN) ? read_in(kxr, (long)(kn * CIN + c) * NG + g, isbf)
                        : read_in(khr, (long)(kn * F + (c - CIN)) * NG + g, isbf);
    Wt[(long)g * K + k] = f2b(v);
}

// ---------- conv2 weight repack: w2b[f][k], k = kt*192 + kn*64 + c ----------
__global__ void repack_w2(const void* __restrict__ w2r, u16* __restrict__ w2b,
                          const int* __restrict__ flag) {
    int idx = blockIdx.x * 256 + threadIdx.x;
    if (idx >= 64 * 576) return;
    int f = idx / 576, k = idx - f * 576;
    int kt = k / 192, rem = k - kt * 192, kn = rem >> 6, c = rem & 63;
    float v = read_in(w2r, (long)((kt * 3 + kn) * 64 + c) * 64 + f, *flag);
    w2b[(long)f * 576 + k] = f2b(v);
}

// ---------- MFMA conv: conv1(on-the-fly) + conv2 as GEMM, 6 timesteps/dispatch ----------
__global__ __launch_bounds__(256)
void conv_mfma(const void* __restrict__ xraw, const float* __restrict__ w1c,
               const float* __restrict__ b1v, const u16* __restrict__ w2b,
               const float* __restrict__ b2v, u16* __restrict__ xs6,
               float* __restrict__ ssq, const int* __restrict__ flag, int g0) {
    constexpr int CP1 = 72;
    __shared__ __align__(16) u16 win1[3 * 66 * CP1];
    __shared__ float sxw[5 * 68];
    __shared__ __align__(16) u16 bch[2 * 2048];
    __shared__ float red[256];

    int tid = threadIdx.x;
    int bb = blockIdx.y, n0 = blockIdx.x * 64, t = g0 * GG + blockIdx.z;
    int w = tid >> 6, l15 = tid & 15, q = (tid >> 4) & 3;
    int isbf = *flag;

    for (int i = tid; i < 5 * 68; i += 256) {
        int r = i / 68, cc = i - r * 68;
        int tt = t - 2 + r, nn = n0 - 2 + cc;
        float v = 0.f;
        if (tt >= 0 && tt < T && nn >= 0 && nn < N)
            v = read_in(xraw, (long)(bb * T + tt) * N + nn, isbf);
        sxw[i] = v;
    }
    __syncthreads();
    for (int i = tid; i < 3 * 66 * 64; i += 256) {
        int c = i & 63, rr = i >> 6;
        int kt = rr / 66, r1 = rr - kt * 66;
        int tt = t - 1 + kt, nn = n0 - 1 + r1;
        u16 o = 0;
        if (tt >= 0 && tt < T && nn >= 0 && nn < N) {
            float v = b1v[c];
            for (int dt = 0; dt < 3; dt++)
#pragma unroll
                for (int dn = 0; dn < 3; dn++)
                    v += sxw[(kt + dt) * 68 + r1 + dn] * w1c[(dt * 3 + dn) * 64 + c];
            o = f2b(v);
        }
        win1[(kt * 66 + r1) * CP1 + c] = o;
    }

    auto stage = [&](int kk, int bufi) {
        int g = tid >> 2, u = tid & 3;
        int k = kk * 32 + ((u ^ (g & 3)) << 3);
#if HAVE_ASYNC
        ASYNC16(w2b + (long)g * 576 + k, &bch[bufi * 2048 + tid * 8]);
#else
        uint4 v = *(const uint4*)(w2b + (long)g * 576 + k);
        *(uint4*)&bch[bufi * 2048 + tid * 8] = v;
#endif
    };
    stage(0, 0);
    __syncthreads();

    floatx4 acc[4] = {};
    for (int kk = 0; kk < 18; ++kk) {
        int cur = kk & 1;
        if (kk + 1 < 18) stage(kk + 1, 1 - cur);
        int kbase = kk * 32;
        int kt = kbase / 192, rem = kbase - kt * 192, kn = rem >> 6, c0 = rem & 63;
        int gcol = w * 16 + l15;
        short8 bf = *(const short8*)&bch[cur * 2048 + gcol * 32 + ((q ^ (gcol & 3)) << 3)];
#pragma unroll
        for (int mi = 0; mi < 4; mi++) {
            short8 af = *(const short8*)&win1[(kt * 66 + mi * 16 + l15 + kn) * CP1 + c0 + q * 8];
            acc[mi] = __builtin_amdgcn_mfma_f32_16x16x32_bf16(af, bf, acc[mi], 0, 0, 0);
        }
        __syncthreads();
    }

    u16* xslice = xs6 + (long)blockIdx.z * B * N * 64;
    int f = w * 16 + l15;
    float bias2 = b2v[f];
    float lsum = 0.f;
#pragma unroll
    for (int mi = 0; mi < 4; mi++)
#pragma unroll
        for (int r = 0; r < 4; r++) {
            int n = n0 + mi * 16 + q * 4 + r;
            float v = acc[mi][r] + bias2;
            lsum += v * v;
            xslice[((long)bb * N + n) * 64 + f] = f2b(v);
        }
    red[tid] = lsum; __syncthreads();
    for (int k = 128; k > 0; k >>= 1) {
        if (tid < k) red[tid] += red[tid + k];
        __syncthreads();
    }
    if (tid == 0) atomicAdd(&ssq[bb * T + t], red[0]);
}

// ---------- MFMA ConvLSTM step, feature-split + 512 threads for occupancy ----------
// grid (4, B, 2): block z computes all 4 gates for features [z*FL, (z+1)*FL).
// Block: 512 thr = 8 waves; M=64 n-rows x NGL = 4*FL local gate-cols.
template<int CIN, int F, int FL>
__global__ __launch_bounds__(512, 4)
void lstm_mfma(const u16* __restrict__ xin, const u16* __restrict__ hprev,
               u16* __restrict__ hnext, float* __restrict__ cst,
               const u16* __restrict__ Wt, const float* __restrict__ bias,
               const float* __restrict__ ssqp, int t) {
    constexpr int CH = CIN + F;
    constexpr int CHP = CH + 8;
    constexpr int K = 3 * CH;
    constexpr int NK = K / 32;
    constexpr int NGL = 4 * FL;          // local cols (256 / 128)
    constexpr int NGP = NGL + 4;
    constexpr int NI = NGL / 128;        // col-frags per wave (2 / 1)
    constexpr int BCH = NGL * 32;        // u16 per B chunk
    constexpr int GLD_USH = 32 * NGP * 2;
    constexpr int UNION_USH = (2 * BCH > GLD_USH) ? 2 * BCH : GLD_USH;
    constexpr int LOGFL = (FL == 64) ? 6 : 5;

    __shared__ __align__(16) u16 win[66 * CHP];
    __shared__ __align__(16) u16 ubuf[UNION_USH];
    u16* bch = ubuf;
    float* Gld = (float*)ubuf;

    int tid = threadIdx.x;
    int bb = blockIdx.y, n0 = blockIdx.x * 64, z = blockIdx.z;
    int w = tid >> 6, l15 = tid & 15, q = (tid >> 4) & 3;

    float scale = 1.f;
    if (ssqp) scale = rsqrtf(fmaxf(ssqp[bb * T + t], 1e-12f));

    constexpr int GRP = CH / 4;
    for (int i = tid; i < 66 * GRP; i += 512) {
        int row = i / GRP, g4 = (i - row * GRP) * 4;
        int n = n0 + row - 1;
        uint2 v{};
        if (n >= 0 && n < N) {
            if (g4 < CIN) {
                v = *(const uint2*)&xin[((long)bb * N + n) * CIN + g4];
                if (ssqp) {
                    u16 e0 = f2b(b2fu((u16)(v.x & 0xFFFF)) * scale);
                    u16 e1 = f2b(b2fu((u16)(v.x >> 16)) * scale);
                    u16 e2 = f2b(b2fu((u16)(v.y & 0xFFFF)) * scale);
                    u16 e3 = f2b(b2fu((u16)(v.y >> 16)) * scale);
                    v.x = (u32)e0 | ((u32)e1 << 16);
                    v.y = (u32)e2 | ((u32)e3 << 16);
                }
            } else if (t > 0) {
                v = *(const uint2*)&hprev[((long)bb * N + n) * F + (g4 - CIN)];
            }
        }
        *(uint2*)&win[row * CHP + g4] = v;
    }

    // stage B chunk kk: local row r = gt*FL+fl -> global gate row gt*F + z*FL + fl
    auto stage = [&](int kk, int bufi) {
#pragma unroll
        for (int it = 0; it < NGL / 128; ++it) {
            int P = it * 512 + tid;
            int r = P >> 2, u = P & 3;
            int gt = r >> LOGFL, fl = r & (FL - 1);
            long g = (long)gt * F + z * FL + fl;
            int k = kk * 32 + ((u ^ (r & 3)) << 3);
#if HAVE_ASYNC
            ASYNC16(Wt + g * K + k, &bch[bufi * BCH + P * 8]);
#else
            uint4 v = *(const uint4*)(Wt + g * K + k);
            *(uint4*)&bch[bufi * BCH + P * 8] = v;
#endif
        }
    };
    stage(0, 0);
    __syncthreads();

    floatx4 acc[4][NI] = {};
    for (int kk = 0; kk < NK; ++kk) {
        int cur = kk & 1;
        if (kk + 1 < NK) stage(kk + 1, 1 - cur);
        int kbase = kk * 32;
        int kn = kbase / CH, c0 = kbase - kn * CH;
        short8 af[4];
#pragma unroll
        for (int mi = 0; mi < 4; mi++)
            af[mi] = *(const short8*)&win[(mi * 16 + l15 + kn) * CHP + c0 + q * 8];
#pragma unroll
        for (int ni = 0; ni < NI; ni++) {
            int r = w * (NI * 16) + ni * 16 + l15;   // local col/row in B
            short8 bf = *(const short8*)&bch[cur * BCH + r * 32 + ((q ^ (r & 3)) << 3)];
#pragma unroll
            for (int mi = 0; mi < 4; mi++)
                acc[mi][ni] = __builtin_amdgcn_mfma_f32_16x16x32_bf16(af[mi], bf, acc[mi][ni], 0, 0, 0);
        }
        __syncthreads();
    }

    // epilogue: 2 halves of 32 m-rows; gate exchange via LDS, fused LSTM pointwise
    for (int h = 0; h < 2; ++h) {
#pragma unroll
        for (int mi2 = 0; mi2 < 2; ++mi2) {
            int mi = h * 2 + mi2;
#pragma unroll
            for (int ni = 0; ni < NI; ni++)
#pragma unroll
                for (int r = 0; r < 4; r++)
                    Gld[(mi2 * 16 + q * 4 + r) * NGP + w * (NI * 16) + ni * 16 + l15] = acc[mi][ni][r];
        }
        __syncthreads();
        for (int i = tid; i < 32 * FL; i += 512) {
            int m = i >> LOGFL, fl = i & (FL - 1);
            int fz = z * FL + fl;
            float gi = Gld[m * NGP + fl]          + bias[fz];
            float gf = Gld[m * NGP + FL + fl]     + bias[F + fz];
            float gc = Gld[m * NGP + 2 * FL + fl] + bias[2 * F + fz];
            float go = Gld[m * NGP + 3 * FL + fl] + bias[3 * F + fz];
            int n = n0 + h * 32 + m;
            long ci = ((long)bb * N + n) * F + fz;
            float cp = (t > 0) ? cst[ci] : 0.f;
            float iv = hsig(gi), fv = hsig(gf), ov = hsig(go);
            float cn = fv * cp + iv * tanhf(gc);
            cst[ci] = cn;
            hnext[ci] = f2b(ov * tanhf(cn));
        }
        __syncthreads();
    }
}

// ---------- final: l2norm per b over N*F2 (bf16 in), project 128->1, flag-dtype store ----------
__global__ void final_kernel(const u16* __restrict__ hT, const float* __restrict__ fcw,
                             const float* __restrict__ fcb, void* __restrict__ out,
                             const int* __restrict__ flag) {
    __shared__ float red[256];
    int b = blockIdx.x, tid = threadIdx.x;
    const u16* hb = hT + (long)b * N * 128;
    float s = 0.f;
    for (int i = tid; i < N * 128; i += 256) { float v = b2fu(hb[i]); s += v * v; }
    red[tid] = s; __syncthreads();
    for (int k = 128; k > 0; k >>= 1) {
        if (tid < k) red[tid] += red[tid + k];
        __syncthreads();
    }
    float scale = rsqrtf(fmaxf(red[0], 1e-12f));
    int n = tid;
    float acc = fcb[0];
    for (int c = 0; c < 128; c++) acc += b2fu(hb[n * 128 + c]) * scale * fcw[c];
    if (*flag) ((bf16*)out)[b * N + n] = __float2bfloat16(acc);
    else       ((float*)out)[b * N + n] = acc;
}

extern "C" void kernel_launch(void* const* d_in, const int* in_sizes, int n_in,
                              void* d_out, int out_size, void* d_ws, size_t ws_size,
                              hipStream_t stream) {
    float* ws = (float*)d_ws;
    u16* xs6   = (u16*)ws;                 // GG*B*N*64 u16 = 3,145,728 fl
    u16* h1A   = (u16*)(ws + 3145728);     // 524,288 fl
    u16* h1B   = (u16*)(ws + 3670016);     // 524,288
    u16* h2A   = (u16*)(ws + 4194304);     // 1,048,576
    u16* h2B   = (u16*)(ws + 5242880);     // 1,048,576
    float* c1  = ws + 6291456;             // 1,048,576
    float* c2  = ws + 7340032;             // 2,097,152
    u16* Wt1   = (u16*)(ws + 9437184);     // 49,152 fl
    u16* Wt2   = (u16*)(ws + 9486336);     // 147,456 fl
    u16* w2b   = (u16*)(ws + 9633792);     // 18,432 fl
    float* w1c  = ws + 9652224;            // 576
    float* bb1  = ws + 9652800;            // 64
    float* bb2  = ws + 9652864;            // 64
    float* bg1  = ws + 9652928;            // 256
    float* bg2  = ws + 9653184;            // 512
    float* fcwf = ws + 9653696;            // 128
    float* fcbf = ws + 9653824;            // 1
    float* ssq  = ws + 9653825;            // 1536
    int*   flag = (int*)(ws + 9655361);    // ~38.6 MB total

    init_flag<<<1, 1, 0, stream>>>(flag);
    detect_scan<<<32, 256, 0, stream>>>((const u16*)d_in[0], flag);

    CvtPack pk;
    pk.d[0] = {d_in[1],  w1c,  576};
    pk.d[1] = {d_in[2],  bb1,  64};
    pk.d[2] = {d_in[4],  bb2,  64};
    pk.d[3] = {d_in[7],  bg1,  256};
    pk.d[4] = {d_in[10], bg2,  512};
    pk.d[5] = {d_in[11], fcwf, 128};
    pk.d[6] = {d_in[12], fcbf, 1};
    pk.d[7] = {nullptr,  ssq,  B * T};
    cvt_pack<<<8, 256, 0, stream>>>(pk, flag);

    repack_w<<<(256 * 384 + 255) / 256, 256, 0, stream>>>(d_in[5], d_in[6], Wt1, 64, 64, flag);
    repack_w<<<(512 * 576 + 255) / 256, 256, 0, stream>>>(d_in[8], d_in[9], Wt2, 64, 128, flag);
    repack_w2<<<(64 * 576 + 255) / 256, 256, 0, stream>>>(d_in[3], w2b, flag);

    for (int g = 0; g < T / GG; g++) {
        conv_mfma<<<dim3(4, B, GG), 256, 0, stream>>>(d_in[0], w1c, bb1, w2b, bb2, xs6, ssq, flag, g);
        for (int ti = 0; ti < GG; ti++) {
            int t = g * GG + ti;
            const u16* h1p = (t & 1) ? h1A : h1B;
            u16* h1n = (t & 1) ? h1B : h1A;
            lstm_mfma<64, 64, 32><<<dim3(4, B, 2), 512, 0, stream>>>(
                xs6 + (long)ti * B * N * 64, h1p, h1n, c1, Wt1, bg1, ssq, t);
            const u16* h2p = (t & 1) ? h2A : h2B;
            u16* h2n = (t & 1) ? h2B : h2A;
            lstm_mfma<64, 128, 64><<<dim3(4, B, 2), 512, 0, stream>>>(
                h1n, h2p, h2n, c2, Wt2, bg2, nullptr, t);
        }
    }
    final_kernel<<<B, 256, 0, stream>>>(h2B, fcwf, fcbf, d_out, flag);
}

// Round 7
// 997.795 us; speedup vs baseline: 7.5322x; 1.0582x over previous
//
#include <hip/hip_runtime.h>
#include <hip/hip_bf16.h>

using bf16 = __hip_bfloat16;
typedef unsigned short u16;
typedef unsigned int u32;
typedef __attribute__((ext_vector_type(8))) short short8;
typedef __attribute__((ext_vector_type(4))) float floatx4;

#define DEVI __device__ __forceinline__

constexpr int B = 64, T = 24, N = 256, F1 = 64, F2 = 128;
constexpr int GG = 8;                    // timesteps per conv group (3 groups)

DEVI float b2f(bf16 v) { return __bfloat162float(v); }
DEVI float b2fu(u16 u) { return __uint_as_float(((u32)u) << 16); }
DEVI u16 f2b(float f) {                  // RNE float->bf16 bits
    u32 u = __float_as_uint(f);
    u32 r = (u + 0x7FFF + ((u >> 16) & 1)) >> 16;
    return (u16)r;
}
DEVI float hsig(float x) { x = x * 0.2f + 0.5f; return fminf(fmaxf(x, 0.f), 1.f); }

#if __has_builtin(__builtin_amdgcn_global_load_lds)
#define ASYNC16(gsrc, ldst)                                                            \
    __builtin_amdgcn_global_load_lds((const __attribute__((address_space(1))) u32*)(gsrc), \
                                     (__attribute__((address_space(3))) u32*)(ldst), 16, 0, 0)
#define HAVE_ASYNC 1
#else
#define HAVE_ASYNC 0
#endif

DEVI float read_in(const void* p, long i, int isbf) {
    return isbf ? b2f(((const bf16*)p)[i]) : ((const float*)p)[i];
}

// ---------- dtype detection ----------
__global__ void init_flag(int* flag) { *flag = 1; }
__global__ void detect_scan(const u16* __restrict__ xu, int* __restrict__ flag) {
    int i0 = blockIdx.x * 2048 + threadIdx.x;
    int hit = 0;
    for (int i = i0; i < (blockIdx.x + 1) * 2048; i += 256)
        if (((xu[i] >> 7) & 0xFF) == 0xFF) hit = 1;
    if (hit) *flag = 0;
}

// ---------- fused setup: convert small tensors to f32 (src=nullptr -> zero-fill) ----------
struct CvtDesc { const void* src; float* dst; int n; };
struct CvtPack { CvtDesc d[8]; };
__global__ void cvt_pack(CvtPack p, const int* __restrict__ flag) {
    CvtDesc c = p.d[blockIdx.x];
    int isbf = *flag;
    for (int i = threadIdx.x; i < c.n; i += 256)
        c.dst[i] = c.src ? read_in(c.src, i, isbf) : 0.f;
}

// ---------- LSTM weight repack: Wt[g][k], k = kn*(CIN+F)+c ; c<CIN -> kx else kh ----------
__global__ void repack_w(const void* __restrict__ kxr, const void* __restrict__ khr,
                         u16* __restrict__ Wt, int CIN, int F, const int* __restrict__ flag) {
    int NG = 4 * F, CH = CIN + F, K = 3 * CH;
    int idx = blockIdx.x * 256 + threadIdx.x;
    if (idx >= NG * K) return;
    int g = idx / K, k = idx - g * K;
    int kn = k / CH, c = k - kn * CH;
    int isbf = *flag;
    float v = (c < CIN) ? read_in(kxr, (long)(kn * CIN + c) * NG + g, isbf)
                        : read_in(khr, (long)(kn * F + (c - CIN)) * NG + g, isbf);
    Wt[(long)g * K + k] = f2b(v);
}

// ---------- conv2 weight repack: w2b[f][k], k = kt*192 + kn*64 + c ----------
__global__ void repack_w2(const void* __restrict__ w2r, u16* __restrict__ w2b,
                          const int* __restrict__ flag) {
    int idx = blockIdx.x * 256 + threadIdx.x;
    if (idx >= 64 * 576) return;
    int f = idx / 576, k = idx - f * 576;
    int kt = k / 192, rem = k - kt * 192, kn = rem >> 6, c = rem & 63;
    float v = read_in(w2r, (long)((kt * 3 + kn) * 64 + c) * 64 + f, *flag);
    w2b[(long)f * 576 + k] = f2b(v);
}

// ---------- conv1 for one group: slices s=0..GG+1 <-> tt = g0*GG-1+s, bf16 out ----------
// c1grp[s][b][n][c]; out-of-range tt -> zero slice (== conv2's SAME zero-pad in t).
__global__ __launch_bounds__(256)
void conv1_grp(const void* __restrict__ xraw, const float* __restrict__ w1c,
               const float* __restrict__ b1v, u16* __restrict__ c1grp,
               const int* __restrict__ flag, int g0) {
    __shared__ float sxw[3 * 260];       // rows tt-1..tt+1, col cc <-> nn = cc-1 (-1..256)
    int s = blockIdx.x, b = blockIdx.y, tid = threadIdx.x;
    int tt = g0 * GG - 1 + s;
    u16* dst = c1grp + ((long)s * B + b) * N * 64;
    if (tt < 0 || tt >= T) {
        for (int i = tid; i < N * 64 / 4; i += 256) *(uint2*)&dst[i * 4] = uint2{0, 0};
        return;
    }
    int isbf = *flag;
    for (int i = tid; i < 3 * 258; i += 256) {
        int r = i / 258, cc = i - r * 258;
        int ttt = tt - 1 + r, nn = cc - 1;
        float v = 0.f;
        if (ttt >= 0 && ttt < T && nn >= 0 && nn < N)
            v = read_in(xraw, (long)(b * T + ttt) * N + nn, isbf);
        sxw[r * 260 + cc] = v;
    }
    __syncthreads();
    int c = tid & 63, ngq = tid >> 6;    // wave-uniform n per lane-group -> sxw broadcast reads
    float w[9];
#pragma unroll
    for (int j = 0; j < 9; j++) w[j] = w1c[j * 64 + c];
    float bias = b1v[c];
    for (int j = 0; j < 64; j++) {
        int n = ngq * 64 + j;
        float v = bias;
#pragma unroll
        for (int dt = 0; dt < 3; dt++)
#pragma unroll
            for (int dn = 0; dn < 3; dn++)
                v += sxw[dt * 260 + n + dn] * w[dt * 3 + dn];
        dst[n * 64 + c] = f2b(v);
    }
}

// ---------- MFMA conv2: stages precomputed conv1 from global, GEMM K=576 ----------
// grid (4, B, GG). Writes UNNORMALIZED bf16 + atomic per-(b,t) sumsq.
__global__ __launch_bounds__(256)
void conv_mfma(const u16* __restrict__ c1grp, const u16* __restrict__ w2b,
               const float* __restrict__ b2v, u16* __restrict__ xs8,
               float* __restrict__ ssq, int g0) {
    constexpr int CP1 = 72;
    __shared__ __align__(16) u16 win1[3 * 66 * CP1];
    __shared__ __align__(16) u16 bch[2 * 2048];
    __shared__ float red[256];

    int tid = threadIdx.x;
    int bb = blockIdx.y, n0 = blockIdx.x * 64, z = blockIdx.z;
    int t = g0 * GG + z;
    int w = tid >> 6, l15 = tid & 15, q = (tid >> 4) & 3;

    // stage A: win1[kt][r1][c] = conv1[tt=t-1+kt][nn=n0-1+r1][c]; slice s = z+kt
    for (int i = tid; i < 3 * 66 * 8; i += 256) {
        int u = i & 7, rr = i >> 3;
        int kt = rr / 66, r1 = rr - kt * 66;
        int nn = n0 - 1 + r1;
        uint4 v{0, 0, 0, 0};
        if (nn >= 0 && nn < N)
            v = *(const uint4*)&c1grp[((((long)(z + kt)) * B + bb) * N + nn) * 64 + u * 8];
        *(uint4*)&win1[(kt * 66 + r1) * CP1 + u * 8] = v;
    }

    auto stage = [&](int kk, int bufi) {
        int g = tid >> 2, u = tid & 3;
        int k = kk * 32 + ((u ^ (g & 3)) << 3);
#if HAVE_ASYNC
        ASYNC16(w2b + (long)g * 576 + k, &bch[bufi * 2048 + tid * 8]);
#else
        uint4 v = *(const uint4*)(w2b + (long)g * 576 + k);
        *(uint4*)&bch[bufi * 2048 + tid * 8] = v;
#endif
    };
    stage(0, 0);
    __syncthreads();

    floatx4 acc[4] = {};
    for (int kk = 0; kk < 18; ++kk) {
        int cur = kk & 1;
        if (kk + 1 < 18) stage(kk + 1, 1 - cur);
        int kbase = kk * 32;
        int kt = kbase / 192, rem = kbase - kt * 192, kn = rem >> 6, c0 = rem & 63;
        int gcol = w * 16 + l15;
        short8 bf = *(const short8*)&bch[cur * 2048 + gcol * 32 + ((q ^ (gcol & 3)) << 3)];
#pragma unroll
        for (int mi = 0; mi < 4; mi++) {
            short8 af = *(const short8*)&win1[(kt * 66 + mi * 16 + l15 + kn) * CP1 + c0 + q * 8];
            acc[mi] = __builtin_amdgcn_mfma_f32_16x16x32_bf16(af, bf, acc[mi], 0, 0, 0);
        }
        __syncthreads();
    }

    u16* xslice = xs8 + (long)z * B * N * 64;
    int f = w * 16 + l15;
    float bias2 = b2v[f];
    float lsum = 0.f;
#pragma unroll
    for (int mi = 0; mi < 4; mi++)
#pragma unroll
        for (int r = 0; r < 4; r++) {
            int n = n0 + mi * 16 + q * 4 + r;
            float v = acc[mi][r] + bias2;
            lsum += v * v;
            xslice[((long)bb * N + n) * 64 + f] = f2b(v);
        }
    red[tid] = lsum; __syncthreads();
    for (int k = 128; k > 0; k >>= 1) {
        if (tid < k) red[tid] += red[tid + k];
        __syncthreads();
    }
    if (tid == 0) atomicAdd(&ssq[bb * T + t], red[0]);
}

// ---------- MFMA ConvLSTM step, feature-split + 512 threads (unchanged from R6) ----------
template<int CIN, int F, int FL>
__global__ __launch_bounds__(512, 4)
void lstm_mfma(const u16* __restrict__ xin, const u16* __restrict__ hprev,
               u16* __restrict__ hnext, float* __restrict__ cst,
               const u16* __restrict__ Wt, const float* __restrict__ bias,
               const float* __restrict__ ssqp, int t) {
    constexpr int CH = CIN + F;
    constexpr int CHP = CH + 8;
    constexpr int K = 3 * CH;
    constexpr int NK = K / 32;
    constexpr int NGL = 4 * FL;
    constexpr int NGP = NGL + 4;
    constexpr int NI = NGL / 128;
    constexpr int BCH = NGL * 32;
    constexpr int GLD_USH = 32 * NGP * 2;
    constexpr int UNION_USH = (2 * BCH > GLD_USH) ? 2 * BCH : GLD_USH;
    constexpr int LOGFL = (FL == 64) ? 6 : 5;

    __shared__ __align__(16) u16 win[66 * CHP];
    __shared__ __align__(16) u16 ubuf[UNION_USH];
    u16* bch = ubuf;
    float* Gld = (float*)ubuf;

    int tid = threadIdx.x;
    int bb = blockIdx.y, n0 = blockIdx.x * 64, z = blockIdx.z;
    int w = tid >> 6, l15 = tid & 15, q = (tid >> 4) & 3;

    float scale = 1.f;
    if (ssqp) scale = rsqrtf(fmaxf(ssqp[bb * T + t], 1e-12f));

    constexpr int GRP = CH / 4;
    for (int i = tid; i < 66 * GRP; i += 512) {
        int row = i / GRP, g4 = (i - row * GRP) * 4;
        int n = n0 + row - 1;
        uint2 v{};
        if (n >= 0 && n < N) {
            if (g4 < CIN) {
                v = *(const uint2*)&xin[((long)bb * N + n) * CIN + g4];
                if (ssqp) {
                    u16 e0 = f2b(b2fu((u16)(v.x & 0xFFFF)) * scale);
                    u16 e1 = f2b(b2fu((u16)(v.x >> 16)) * scale);
                    u16 e2 = f2b(b2fu((u16)(v.y & 0xFFFF)) * scale);
                    u16 e3 = f2b(b2fu((u16)(v.y >> 16)) * scale);
                    v.x = (u32)e0 | ((u32)e1 << 16);
                    v.y = (u32)e2 | ((u32)e3 << 16);
                }
            } else if (t > 0) {
                v = *(const uint2*)&hprev[((long)bb * N + n) * F + (g4 - CIN)];
            }
        }
        *(uint2*)&win[row * CHP + g4] = v;
    }

    auto stage = [&](int kk, int bufi) {
#pragma unroll
        for (int it = 0; it < NGL / 128; ++it) {
            int P = it * 512 + tid;
            int r = P >> 2, u = P & 3;
            int gt = r >> LOGFL, fl = r & (FL - 1);
            long g = (long)gt * F + z * FL + fl;
            int k = kk * 32 + ((u ^ (r & 3)) << 3);
#if HAVE_ASYNC
            ASYNC16(Wt + g * K + k, &bch[bufi * BCH + P * 8]);
#else
            uint4 v = *(const uint4*)(Wt + g * K + k);
            *(uint4*)&bch[bufi * BCH + P * 8] = v;
#endif
        }
    };
    stage(0, 0);
    __syncthreads();

    floatx4 acc[4][NI] = {};
    for (int kk = 0; kk < NK; ++kk) {
        int cur = kk & 1;
        if (kk + 1 < NK) stage(kk + 1, 1 - cur);
        int kbase = kk * 32;
        int kn = kbase / CH, c0 = kbase - kn * CH;
        short8 af[4];
#pragma unroll
        for (int mi = 0; mi < 4; mi++)
            af[mi] = *(const short8*)&win[(mi * 16 + l15 + kn) * CHP + c0 + q * 8];
#pragma unroll
        for (int ni = 0; ni < NI; ni++) {
            int r = w * (NI * 16) + ni * 16 + l15;
            short8 bf = *(const short8*)&bch[cur * BCH + r * 32 + ((q ^ (r & 3)) << 3)];
#pragma unroll
            for (int mi = 0; mi < 4; mi++)
                acc[mi][ni] = __builtin_amdgcn_mfma_f32_16x16x32_bf16(af[mi], bf, acc[mi][ni], 0, 0, 0);
        }
        __syncthreads();
    }

    for (int h = 0; h < 2; ++h) {
#pragma unroll
        for (int mi2 = 0; mi2 < 2; ++mi2) {
            int mi = h * 2 + mi2;
#pragma unroll
            for (int ni = 0; ni < NI; ni++)
#pragma unroll
                for (int r = 0; r < 4; r++)
                    Gld[(mi2 * 16 + q * 4 + r) * NGP + w * (NI * 16) + ni * 16 + l15] = acc[mi][ni][r];
        }
        __syncthreads();
        for (int i = tid; i < 32 * FL; i += 512) {
            int m = i >> LOGFL, fl = i & (FL - 1);
            int fz = z * FL + fl;
            float gi = Gld[m * NGP + fl]          + bias[fz];
            float gf = Gld[m * NGP + FL + fl]     + bias[F + fz];
            float gc = Gld[m * NGP + 2 * FL + fl] + bias[2 * F + fz];
            float go = Gld[m * NGP + 3 * FL + fl] + bias[3 * F + fz];
            int n = n0 + h * 32 + m;
            long ci = ((long)bb * N + n) * F + fz;
            float cp = (t > 0) ? cst[ci] : 0.f;
            float iv = hsig(gi), fv = hsig(gf), ov = hsig(go);
            float cn = fv * cp + iv * tanhf(gc);
            cst[ci] = cn;
            hnext[ci] = f2b(ov * tanhf(cn));
        }
        __syncthreads();
    }
}

// ---------- final: l2norm per b over N*F2 (bf16 in), project 128->1, flag-dtype store ----------
__global__ void final_kernel(const u16* __restrict__ hT, const float* __restrict__ fcw,
                             const float* __restrict__ fcb, void* __restrict__ out,
                             const int* __restrict__ flag) {
    __shared__ float red[256];
    int b = blockIdx.x, tid = threadIdx.x;
    const u16* hb = hT + (long)b * N * 128;
    float s = 0.f;
    for (int i = tid; i < N * 128; i += 256) { float v = b2fu(hb[i]); s += v * v; }
    red[tid] = s; __syncthreads();
    for (int k = 128; k > 0; k >>= 1) {
        if (tid < k) red[tid] += red[tid + k];
        __syncthreads();
    }
    float scale = rsqrtf(fmaxf(red[0], 1e-12f));
    int n = tid;
    float acc = fcb[0];
    for (int c = 0; c < 128; c++) acc += b2fu(hb[n * 128 + c]) * scale * fcw[c];
    if (*flag) ((bf16*)out)[b * N + n] = __float2bfloat16(acc);
    else       ((float*)out)[b * N + n] = acc;
}

extern "C" void kernel_launch(void* const* d_in, const int* in_sizes, int n_in,
                              void* d_out, int out_size, void* d_ws, size_t ws_size,
                              hipStream_t stream) {
    float* ws = (float*)d_ws;
    u16* xs8    = (u16*)ws;                 // GG*B*N*64 u16 = 4,194,304 fl
    u16* c1grp  = (u16*)(ws + 4194304);     // (GG+2)*B*N*64 u16 = 5,242,880 fl
    u16* h1A    = (u16*)(ws + 9437184);     // 524,288 fl
    u16* h1B    = (u16*)(ws + 9961472);     // 524,288
    u16* h2A    = (u16*)(ws + 10485760);    // 1,048,576
    u16* h2B    = (u16*)(ws + 11534336);    // 1,048,576
    float* c1   = ws + 12582912;            // 1,048,576
    float* c2   = ws + 13631488;            // 2,097,152
    u16* Wt1    = (u16*)(ws + 15728640);    // 49,152 fl
    u16* Wt2    = (u16*)(ws + 15777792);    // 147,456 fl
    u16* w2b    = (u16*)(ws + 15925248);    // 18,432 fl
    float* w1c  = ws + 15943680;            // 576
    float* bb1  = ws + 15944256;            // 64
    float* bb2  = ws + 15944320;            // 64
    float* bg1  = ws + 15944384;            // 256
    float* bg2  = ws + 15944640;            // 512
    float* fcwf = ws + 15945152;            // 128
    float* fcbf = ws + 15945280;            // 1
    float* ssq  = ws + 15945281;            // 1536
    int*   flag = (int*)(ws + 15946817);    // total ~15.95M fl = 63.8 MB

    init_flag<<<1, 1, 0, stream>>>(flag);
    detect_scan<<<32, 256, 0, stream>>>((const u16*)d_in[0], flag);

    CvtPack pk;
    pk.d[0] = {d_in[1],  w1c,  576};
    pk.d[1] = {d_in[2],  bb1,  64};
    pk.d[2] = {d_in[4],  bb2,  64};
    pk.d[3] = {d_in[7],  bg1,  256};
    pk.d[4] = {d_in[10], bg2,  512};
    pk.d[5] = {d_in[11], fcwf, 128};
    pk.d[6] = {d_in[12], fcbf, 1};
    pk.d[7] = {nullptr,  ssq,  B * T};
    cvt_pack<<<8, 256, 0, stream>>>(pk, flag);

    repack_w<<<(256 * 384 + 255) / 256, 256, 0, stream>>>(d_in[5], d_in[6], Wt1, 64, 64, flag);
    repack_w<<<(512 * 576 + 255) / 256, 256, 0, stream>>>(d_in[8], d_in[9], Wt2, 64, 128, flag);
    repack_w2<<<(64 * 576 + 255) / 256, 256, 0, stream>>>(d_in[3], w2b, flag);

    for (int g = 0; g < T / GG; g++) {
        conv1_grp<<<dim3(GG + 2, B), 256, 0, stream>>>(d_in[0], w1c, bb1, c1grp, flag, g);
        conv_mfma<<<dim3(4, B, GG), 256, 0, stream>>>(c1grp, w2b, bb2, xs8, ssq, g);
        for (int ti = 0; ti < GG; ti++) {
            int t = g * GG + ti;
            const u16* h1p = (t & 1) ? h1A : h1B;
            u16* h1n = (t & 1) ? h1B : h1A;
            lstm_mfma<64, 64, 32><<<dim3(4, B, 2), 512, 0, stream>>>(
                xs8 + (long)ti * B * N * 64, h1p, h1n, c1, Wt1, bg1, ssq, t);
            const u16* h2p = (t & 1) ? h2A : h2B;
            u16* h2n = (t & 1) ? h2B : h2A;
            lstm_mfma<64, 128, 64><<<dim3(4, B, 2), 512, 0, stream>>>(
                h1n, h2p, h2n, c2, Wt2, bg2, nullptr, t);
        }
    }
    final_kernel<<<B, 256, 0, stream>>>(h2B, fcwf, fcbf, d_out, flag);
}